// Round 4
// baseline (975.754 us; speedup 1.0000x reference)
//
#include <hip/hip_runtime.h>
#include <math.h>

typedef __bf16 bf16x8 __attribute__((ext_vector_type(8)));
typedef float f32x16 __attribute__((ext_vector_type(16)));
typedef unsigned int uint4v __attribute__((ext_vector_type(4)));

__device__ __forceinline__ unsigned short bf16_rne(float f) {
    unsigned u = __float_as_uint(f);
    unsigned r = u + 0x7fffu + ((u >> 16) & 1u);
    return (unsigned short)(r >> 16);
}
__device__ __forceinline__ float bf16_to_f(unsigned short h) {
    return __uint_as_float(((unsigned)h) << 16);
}

// ---------------------------------------------------------------------------
__device__ __forceinline__ float block_sum256(float v, float* red) {
    #pragma unroll
    for (int off = 32; off > 0; off >>= 1)
        v += __shfl_down(v, off, 64);
    const int tid = threadIdx.x;
    if ((tid & 63) == 0) red[tid >> 6] = v;
    __syncthreads();
    float tot = red[0] + red[1] + red[2] + red[3];
    __syncthreads();
    return tot;
}

__device__ __forceinline__ void l2n_lds(float* a, int n, float* red) {
    float s = 0.f;
    for (int i = threadIdx.x; i < n; i += 256) s += a[i] * a[i];
    const float tot = block_sum256(s, red);
    const float sc = 1.0f / (sqrtf(tot) + 1e-12f);
    for (int i = threadIdx.x; i < n; i += 256) a[i] *= sc;
    __syncthreads();
}

// ---------------------------------------------------------------------------
// skew + fantastic_four -> kf (layout [o][i][3][3])
// ---------------------------------------------------------------------------
__global__ __launch_bounds__(256) void ff_kernel(
    const float* __restrict__ wr,
    const float* __restrict__ u1g, const float* __restrict__ u2g,
    const float* __restrict__ u3g, const float* __restrict__ u4g,
    float* __restrict__ kf_out)
{
    __shared__ float ks[9216];
    __shared__ float u1[96], v1[96], u2[96], v2[96];
    __shared__ float u3[288], u4[288], v3[32], v4[32];
    __shared__ float red[8];
    const int tid = threadIdx.x;

    for (int i = tid; i < 9216; i += 256) {
        int q  = i % 3;
        int p  = (i / 3) % 3;
        int ic = (i / 9) % 32;
        int oc = i / 288;
        ks[i] = wr[i] - wr[ic * 288 + oc * 9 + (2 - p) * 3 + (2 - q)];
    }
    if (tid < 96) { u1[tid] = u1g[tid]; u2[tid] = u2g[tid]; }
    for (int i = tid; i < 288; i += 256) { u3[i] = u3g[i]; u4[i] = u4g[i]; }
    __syncthreads();
    l2n_lds(u1, 96, red);
    l2n_lds(u2, 96, red);
    l2n_lds(u3, 288, red);
    l2n_lds(u4, 288, red);

    for (int it = 0; it < 3; ++it) {
        if (tid < 96) {
            int o = tid / 3, p = tid % 3;
            float s = 0.f;
            for (int i = 0; i < 32; ++i)
                for (int q = 0; q < 3; ++q)
                    s += ks[o * 288 + i * 9 + p * 3 + q] * u1[i * 3 + q];
            v1[tid] = s;
        }
        __syncthreads();
        l2n_lds(v1, 96, red);
        if (tid < 96) {
            int i = tid / 3, q = tid % 3;
            float s = 0.f;
            for (int o = 0; o < 32; ++o)
                for (int p = 0; p < 3; ++p)
                    s += ks[o * 288 + i * 9 + p * 3 + q] * v1[o * 3 + p];
            u1[tid] = s;
        }
        __syncthreads();
        l2n_lds(u1, 96, red);
        if (tid < 96) {
            int o = tid / 3, q = tid % 3;
            float s = 0.f;
            for (int i = 0; i < 32; ++i)
                for (int p = 0; p < 3; ++p)
                    s += ks[o * 288 + i * 9 + p * 3 + q] * u2[i * 3 + p];
            v2[tid] = s;
        }
        __syncthreads();
        l2n_lds(v2, 96, red);
        if (tid < 96) {
            int i = tid / 3, p = tid % 3;
            float s = 0.f;
            for (int o = 0; o < 32; ++o)
                for (int q = 0; q < 3; ++q)
                    s += ks[o * 288 + i * 9 + p * 3 + q] * v2[o * 3 + q];
            u2[tid] = s;
        }
        __syncthreads();
        l2n_lds(u2, 96, red);
        if (tid < 32) {
            float s = 0.f;
            for (int i = 0; i < 32; ++i)
                for (int pq = 0; pq < 9; ++pq)
                    s += ks[tid * 288 + i * 9 + pq] * u3[i * 9 + pq];
            v3[tid] = s;
        }
        __syncthreads();
        l2n_lds(v3, 32, red);
        for (int j = tid; j < 288; j += 256) {
            float s = 0.f;
            for (int o = 0; o < 32; ++o)
                s += ks[o * 288 + j] * v3[o];
            u3[j] = s;
        }
        __syncthreads();
        l2n_lds(u3, 288, red);
        if (tid < 32) {
            float s = 0.f;
            for (int o = 0; o < 32; ++o)
                for (int pq = 0; pq < 9; ++pq)
                    s += ks[o * 288 + tid * 9 + pq] * u4[o * 9 + pq];
            v4[tid] = s;
        }
        __syncthreads();
        l2n_lds(v4, 32, red);
        for (int j = tid; j < 288; j += 256) {
            int o = j / 9, pq = j - o * 9;
            float s = 0.f;
            for (int i = 0; i < 32; ++i)
                s += ks[o * 288 + i * 9 + pq] * v4[i];
            u4[j] = s;
        }
        __syncthreads();
        l2n_lds(u4, 288, red);
    }

    float p1 = 0.f, p2 = 0.f, p3 = 0.f, p4 = 0.f;
    for (int idx = tid; idx < 9216; idx += 256) {
        int q = idx % 3;
        int p = (idx / 3) % 3;
        int i = (idx / 9) % 32;
        int o = idx / 288;
        float k = ks[idx];
        p1 += k * u1[i * 3 + q] * v1[o * 3 + p];
        p2 += k * u2[i * 3 + p] * v2[o * 3 + q];
        p3 += k * u3[i * 9 + p * 3 + q] * v3[o];
        p4 += k * u4[o * 9 + p * 3 + q] * v4[i];
    }
    float s1 = block_sum256(p1, red);
    float s2 = block_sum256(p2, red);
    float s3 = block_sum256(p3, red);
    float s4 = block_sum256(p4, red);
    float sigma = fminf(fminf(s1, s2), fminf(s3, s4));
    for (int idx = tid; idx < 9216; idx += 256)
        kf_out[idx] = ks[idx] / sigma;
}

// ---------------------------------------------------------------------------
// wacc init: identity + base kernel centered in 11x11. wacc layout [o][c][11][11]
// ---------------------------------------------------------------------------
__global__ void initacc_kernel(const float* __restrict__ kf, float* __restrict__ wacc) {
    int idx = blockIdx.x * 256 + threadIdx.x;
    if (idx >= 123904) return;
    int o = idx / 3872;
    int rem = idx - o * 3872;
    int c = rem / 121;
    int yx = rem - c * 121;
    int y = yx / 11, x = yx - y * 11;
    float v = (o == c && y == 5 && x == 5) ? 1.0f : 0.0f;
    if (y >= 4 && y <= 6 && x >= 4 && x <= 6)
        v += kf[o * 288 + c * 9 + (y - 4) * 3 + (x - 4)];
    wacc[idx] = v;
}

// ---------------------------------------------------------------------------
// conv-exponential step
// ---------------------------------------------------------------------------
__global__ void expstep_kernel(const float* __restrict__ kf, const float* __restrict__ ki,
                               float* __restrict__ ko, float* __restrict__ wacc,
                               int S, float scale)
{
    const int S2 = S + 2;
    const int off = (11 - S2) >> 1;
    const int o = blockIdx.x >> 5;
    const int d = blockIdx.x & 31;
    for (int yx = threadIdx.x; yx < S2 * S2; yx += blockDim.x) {
        int y = yx / S2, xx = yx - y * S2;
        float s = 0.f;
        for (int c = 0; c < 32; ++c) {
            const float* kfo = kf + o * 288 + c * 9;
            const float* kic = ki + (c * 32 + d) * S * S;
            #pragma unroll
            for (int p = 0; p < 3; ++p) {
                int yy = y - p;
                if (yy < 0 || yy >= S) continue;
                #pragma unroll
                for (int q = 0; q < 3; ++q) {
                    int xq = xx - q;
                    if (xq < 0 || xq >= S) continue;
                    s += kfo[p * 3 + q] * kic[yy * S + xq];
                }
            }
        }
        s *= scale;
        ko[(o * 32 + d) * S2 * S2 + yx] = s;
        wacc[(o * 32 + d) * 121 + (y + off) * 11 + (xx + off)] += s;
    }
}

// ---------------------------------------------------------------------------
// Weight prepack: wacc [o][c][11][11] fp32 -> wbuf bf16 A-fragments.
// Frag index = ((tap*2 + chalf)*2 + split)*64 + lane ; each entry = uint4
// (8 bf16): lane(m=lane&31, khalf=lane>>5), j -> c = chalf*16 + khalf*8 + j.
// split 0 = bf16 hi, split 1 = bf16 lo (residual).
// ---------------------------------------------------------------------------
__global__ void wprep_kernel(const float* __restrict__ wacc, uint4v* __restrict__ wbuf) {
    int idx = blockIdx.x * 256 + threadIdx.x;   // 121*2*2*64 = 30976
    if (idx >= 30976) return;
    int lane  = idx & 63;
    int split = (idx >> 6) & 1;
    int ch    = (idx >> 7) & 1;
    int tap   = idx >> 8;                       // p*11+q
    int o     = lane & 31;
    int cbase = ch * 16 + ((lane >> 5) << 3);
    unsigned short v[8];
    #pragma unroll
    for (int j = 0; j < 8; ++j) {
        float w = wacc[o * 3872 + (cbase + j) * 121 + tap];
        unsigned short h = bf16_rne(w);
        v[j] = split ? bf16_rne(w - bf16_to_f(h)) : h;
    }
    uint4v u;
    u.x = (unsigned)v[0] | ((unsigned)v[1] << 16);
    u.y = (unsigned)v[2] | ((unsigned)v[3] << 16);
    u.z = (unsigned)v[4] | ((unsigned)v[5] << 16);
    u.w = (unsigned)v[6] | ((unsigned)v[7] << 16);
    wbuf[idx] = u;
}

// ---------------------------------------------------------------------------
// Main conv via bf16-split MFMA (w=whi+wlo, x=xhi+xlo; per tap/c-half the 3
// terms whi*xhi + wlo*xhi + whi*xlo accumulate additively -> rel err ~2^-16).
//
// OCCUPANCY RESTRUCTURE (this round): the hi and lo x-planes are never needed
// at the same time (terms Ah*Bh, Al*Bh read x-hi; Ah*Bl reads x-lo). So LDS
// holds ONE 35 KB plane buffer, 4 phases per block:
//   stage hi(ch0) ; bar ; 2-pass MFMA ; bar ;
//   stage lo(ch0, re-read x) ; bar ; 1-pass MFMA ; bar ; ... repeat ch1.
// LDS 70 KB -> 35 KB and __launch_bounds__(256,3) => 3 blocks/CU, 12 waves/CU
// (was 2 blocks / 8 waves). Rationale: rounds 1-3 proved conflicts, ILP
// scheduling, and stage de-phasing are all null at 2 waves/SIMD; MfmaUtil is
// pinned at ~60% because 2 waves/SIMD cannot keep the matrix pipe fed.
// +50% TLP and 3 independently-phased blocks/CU attack exactly that.
// Deliberately NOT reg-stashing the lo plane: +40 VGPRs would push the total
// past 170 and drop back to 2 waves/SIMD. x is read twice per c-half instead
// (HBM is at 9% of peak; measured harmless in round 3).
//
// Buffer layout: [khalf][px][8ch] ushort (conflict-free, verified: 0).
// mfma_f32_32x32x16_bf16: A[m=lane&31][k=(lane>>5)*8+j], B[k][n=lane&31],
// D: col=lane&31, row=(r&3)+8*(r>>2)+4*(lane>>5)  [m74/m101 verified C/D].
// ---------------------------------------------------------------------------
__device__ __forceinline__ void pack2(unsigned short* dst, const unsigned short* v) {
    uint4v u;
    u.x = (unsigned)v[0] | ((unsigned)v[1] << 16);
    u.y = (unsigned)v[2] | ((unsigned)v[3] << 16);
    u.z = (unsigned)v[4] | ((unsigned)v[5] << 16);
    u.w = (unsigned)v[6] | ((unsigned)v[7] << 16);
    *(uint4v*)dst = u;
}

__device__ __forceinline__ void stage_plane(
    unsigned short* __restrict__ buf, const float* __restrict__ x,
    int b, int chlf, bool lo, int Y0, int X0, int tid)
{
    const float* xb = x + (((size_t)(b * 32 + chlf * 16)) << 16);
    for (int pix = tid; pix < 1092; pix += 256) {
        int r = pix / 42, s = pix - r * 42;
        int gy = (Y0 + r - 5) & 255;
        int gx = (X0 + s - 5) & 255;
        const float* xp = xb + (gy << 8) + gx;
        unsigned short v[16];
        #pragma unroll
        for (int cc = 0; cc < 16; ++cc) {
            float t = xp[(size_t)cc << 16];
            unsigned short h = bf16_rne(t);
            v[cc] = lo ? bf16_rne(t - bf16_to_f(h)) : h;
        }
        pack2(&buf[pix * 8], v);
        pack2(&buf[(1092 + pix) * 8], v + 8);
    }
}

template<bool TWOPASS>
__device__ __forceinline__ void mfma_pass(
    f32x16 (&acc)[4],
    const uint4v* __restrict__ wbuf,
    const uint4v* __restrict__ pb,
    int chlf, int lane, int ywave, int myoff)
{
    const int wb0 = chlf * 128 + lane;
    #pragma unroll 1
    for (int q = 0; q < 11; ++q) {
        uint4v ah[8], al[8];
        ah[0] = wbuf[wb0 + q * 256];
        ah[1] = wbuf[wb0 + (11 + q) * 256];
        ah[2] = wbuf[wb0 + (22 + q) * 256];
        if (TWOPASS) {
            al[0] = wbuf[wb0 + q * 256 + 64];
            al[1] = wbuf[wb0 + (11 + q) * 256 + 64];
            al[2] = wbuf[wb0 + (22 + q) * 256 + 64];
        }
        bf16x8 B = __builtin_bit_cast(bf16x8, pb[ywave * 42 + q + myoff]);
        #pragma unroll
        for (int r = 0; r < 14; ++r) {
            const bf16x8 cB = B;
            if (r < 13)
                B = __builtin_bit_cast(bf16x8, pb[(ywave + r + 1) * 42 + q + myoff]);
            if (r + 3 <= 10) {
                ah[(r + 3) & 7] = wbuf[wb0 + ((r + 3) * 11 + q) * 256];
                if (TWOPASS)
                    al[(r + 3) & 7] = wbuf[wb0 + ((r + 3) * 11 + q) * 256 + 64];
            }
            const int plo = (r - 3 > 0) ? r - 3 : 0;
            const int phi = (r < 10) ? r : 10;
            __builtin_amdgcn_s_setprio(1);
            #pragma unroll
            for (int p = plo; p <= phi; ++p)
                acc[r - p] = __builtin_amdgcn_mfma_f32_32x32x16_bf16(
                    __builtin_bit_cast(bf16x8, ah[p & 7]), cB, acc[r - p], 0, 0, 0);
            if (TWOPASS) {
                #pragma unroll
                for (int p = plo; p <= phi; ++p)
                    acc[r - p] = __builtin_amdgcn_mfma_f32_32x32x16_bf16(
                        __builtin_bit_cast(bf16x8, al[p & 7]), cB, acc[r - p], 0, 0, 0);
            }
            __builtin_amdgcn_s_setprio(0);
        }
    }
}

__global__ __launch_bounds__(256, 3) void conv_mfma_kernel(
    const float* __restrict__ x, const uint4v* __restrict__ wbuf,
    const float* __restrict__ bias, float* __restrict__ out)
{
    __shared__ unsigned short sbuf[2 * 1092 * 8];   // 34944 B single plane
    __shared__ float biasS[32];

    const int b    = blockIdx.z;
    const int Y0   = blockIdx.y << 4;
    const int X0   = blockIdx.x << 5;
    const int tid  = threadIdx.x;
    const int lane = tid & 63;
    const int ywave = (tid >> 6) << 2;                    // wave's first out row
    const int myoff = (lane & 31) + (lane >> 5) * 1092;   // 16B-unit offset

    if (tid < 32) biasS[tid] = bias[tid];

    f32x16 acc[4];
    #pragma unroll
    for (int s = 0; s < 4; ++s)
        #pragma unroll
        for (int r = 0; r < 16; ++r) acc[s][r] = 0.f;

    const uint4v* pb = (const uint4v*)sbuf;

    #pragma unroll 1
    for (int chlf = 0; chlf < 2; ++chlf) {
        // phase A: hi plane, 2-pass (w_hi*x_hi + w_lo*x_hi)
        stage_plane(sbuf, x, b, chlf, false, Y0, X0, tid);
        __syncthreads();
        mfma_pass<true>(acc, wbuf, pb, chlf, lane, ywave, myoff);
        __syncthreads();
        // phase B: lo plane, 1-pass (w_hi*x_lo)
        stage_plane(sbuf, x, b, chlf, true, Y0, X0, tid);
        __syncthreads();
        mfma_pass<false>(acc, wbuf, pb, chlf, lane, ywave, myoff);
        __syncthreads();
    }

    // ---- epilogue: bias + store (lane = x col, reg -> o channel) ----
    const int colx = X0 + (lane & 31);
    const int half = lane >> 5;
    #pragma unroll
    for (int s = 0; s < 4; ++s) {
        int y = Y0 + ywave + s;
        #pragma unroll
        for (int r = 0; r < 16; ++r) {
            int o = (r & 3) + ((r >> 2) << 3) + (half << 2);
            out[(((size_t)(b * 32 + o)) << 16) + (y << 8) + colx] = acc[s][r] + biasS[o];
        }
    }
}

// ---------------------------------------------------------------------------
extern "C" void kernel_launch(void* const* d_in, const int* in_sizes, int n_in,
                              void* d_out, int out_size, void* d_ws, size_t ws_size,
                              hipStream_t stream) {
    const float* x    = (const float*)d_in[0];
    const float* wraw = (const float*)d_in[1];
    const float* bias = (const float*)d_in[2];
    const float* u1   = (const float*)d_in[3];
    const float* u2   = (const float*)d_in[4];
    const float* u3   = (const float*)d_in[5];
    const float* u4   = (const float*)d_in[6];
    float* out = (float*)d_out;

    float* ws   = (float*)d_ws;
    float* kf   = ws;               // 9216
    float* bufA = kf + 9216;        // 123904
    float* bufB = bufA + 123904;    // 123904
    float* wacc = bufB + 123904;    // 123904
    uint4v* wbuf = (uint4v*)(wacc + 123904);  // 30976 uint4 = 495616 B

    ff_kernel<<<1, 256, 0, stream>>>(wraw, u1, u2, u3, u4, kf);
    initacc_kernel<<<484, 256, 0, stream>>>(kf, wacc);
    expstep_kernel<<<1024, 128, 0, stream>>>(kf, kf,   bufA, wacc, 3, 0.5f);
    expstep_kernel<<<1024, 128, 0, stream>>>(kf, bufA, bufB, wacc, 5, 1.0f / 3.0f);
    expstep_kernel<<<1024, 128, 0, stream>>>(kf, bufB, bufA, wacc, 7, 0.25f);
    expstep_kernel<<<1024, 128, 0, stream>>>(kf, bufA, bufB, wacc, 9, 0.2f);
    wprep_kernel<<<121, 256, 0, stream>>>(wacc, wbuf);

    conv_mfma_kernel<<<dim3(8, 16, 16), 256, 0, stream>>>(x, wbuf, bias, out);
}

// Round 5
// 894.015 us; speedup vs baseline: 1.0914x; 1.0914x over previous
//
#include <hip/hip_runtime.h>
#include <math.h>

typedef __bf16 bf16x8 __attribute__((ext_vector_type(8)));
typedef float f32x16 __attribute__((ext_vector_type(16)));
typedef unsigned int uint4v __attribute__((ext_vector_type(4)));

__device__ __forceinline__ unsigned short bf16_rne(float f) {
    unsigned u = __float_as_uint(f);
    unsigned r = u + 0x7fffu + ((u >> 16) & 1u);
    return (unsigned short)(r >> 16);
}
__device__ __forceinline__ float bf16_to_f(unsigned short h) {
    return __uint_as_float(((unsigned)h) << 16);
}

// ---------------------------------------------------------------------------
__device__ __forceinline__ float block_sum256(float v, float* red) {
    #pragma unroll
    for (int off = 32; off > 0; off >>= 1)
        v += __shfl_down(v, off, 64);
    const int tid = threadIdx.x;
    if ((tid & 63) == 0) red[tid >> 6] = v;
    __syncthreads();
    float tot = red[0] + red[1] + red[2] + red[3];
    __syncthreads();
    return tot;
}

__device__ __forceinline__ void l2n_lds(float* a, int n, float* red) {
    float s = 0.f;
    for (int i = threadIdx.x; i < n; i += 256) s += a[i] * a[i];
    const float tot = block_sum256(s, red);
    const float sc = 1.0f / (sqrtf(tot) + 1e-12f);
    for (int i = threadIdx.x; i < n; i += 256) a[i] *= sc;
    __syncthreads();
}

// ---------------------------------------------------------------------------
// skew + fantastic_four -> kf (layout [o][i][3][3])
// ---------------------------------------------------------------------------
__global__ __launch_bounds__(256) void ff_kernel(
    const float* __restrict__ wr,
    const float* __restrict__ u1g, const float* __restrict__ u2g,
    const float* __restrict__ u3g, const float* __restrict__ u4g,
    float* __restrict__ kf_out)
{
    __shared__ float ks[9216];
    __shared__ float u1[96], v1[96], u2[96], v2[96];
    __shared__ float u3[288], u4[288], v3[32], v4[32];
    __shared__ float red[8];
    const int tid = threadIdx.x;

    for (int i = tid; i < 9216; i += 256) {
        int q  = i % 3;
        int p  = (i / 3) % 3;
        int ic = (i / 9) % 32;
        int oc = i / 288;
        ks[i] = wr[i] - wr[ic * 288 + oc * 9 + (2 - p) * 3 + (2 - q)];
    }
    if (tid < 96) { u1[tid] = u1g[tid]; u2[tid] = u2g[tid]; }
    for (int i = tid; i < 288; i += 256) { u3[i] = u3g[i]; u4[i] = u4g[i]; }
    __syncthreads();
    l2n_lds(u1, 96, red);
    l2n_lds(u2, 96, red);
    l2n_lds(u3, 288, red);
    l2n_lds(u4, 288, red);

    for (int it = 0; it < 3; ++it) {
        if (tid < 96) {
            int o = tid / 3, p = tid % 3;
            float s = 0.f;
            for (int i = 0; i < 32; ++i)
                for (int q = 0; q < 3; ++q)
                    s += ks[o * 288 + i * 9 + p * 3 + q] * u1[i * 3 + q];
            v1[tid] = s;
        }
        __syncthreads();
        l2n_lds(v1, 96, red);
        if (tid < 96) {
            int i = tid / 3, q = tid % 3;
            float s = 0.f;
            for (int o = 0; o < 32; ++o)
                for (int p = 0; p < 3; ++p)
                    s += ks[o * 288 + i * 9 + p * 3 + q] * v1[o * 3 + p];
            u1[tid] = s;
        }
        __syncthreads();
        l2n_lds(u1, 96, red);
        if (tid < 96) {
            int o = tid / 3, q = tid % 3;
            float s = 0.f;
            for (int i = 0; i < 32; ++i)
                for (int p = 0; p < 3; ++p)
                    s += ks[o * 288 + i * 9 + p * 3 + q] * u2[i * 3 + p];
            v2[tid] = s;
        }
        __syncthreads();
        l2n_lds(v2, 96, red);
        if (tid < 96) {
            int i = tid / 3, p = tid % 3;
            float s = 0.f;
            for (int o = 0; o < 32; ++o)
                for (int q = 0; q < 3; ++q)
                    s += ks[o * 288 + i * 9 + p * 3 + q] * v2[o * 3 + q];
            u2[tid] = s;
        }
        __syncthreads();
        l2n_lds(u2, 96, red);
        if (tid < 32) {
            float s = 0.f;
            for (int i = 0; i < 32; ++i)
                for (int pq = 0; pq < 9; ++pq)
                    s += ks[tid * 288 + i * 9 + pq] * u3[i * 9 + pq];
            v3[tid] = s;
        }
        __syncthreads();
        l2n_lds(v3, 32, red);
        for (int j = tid; j < 288; j += 256) {
            float s = 0.f;
            for (int o = 0; o < 32; ++o)
                s += ks[o * 288 + j] * v3[o];
            u3[j] = s;
        }
        __syncthreads();
        l2n_lds(u3, 288, red);
        if (tid < 32) {
            float s = 0.f;
            for (int o = 0; o < 32; ++o)
                for (int pq = 0; pq < 9; ++pq)
                    s += ks[o * 288 + tid * 9 + pq] * u4[o * 9 + pq];
            v4[tid] = s;
        }
        __syncthreads();
        l2n_lds(v4, 32, red);
        for (int j = tid; j < 288; j += 256) {
            int o = j / 9, pq = j - o * 9;
            float s = 0.f;
            for (int i = 0; i < 32; ++i)
                s += ks[o * 288 + i * 9 + pq] * v4[i];
            u4[j] = s;
        }
        __syncthreads();
        l2n_lds(u4, 288, red);
    }

    float p1 = 0.f, p2 = 0.f, p3 = 0.f, p4 = 0.f;
    for (int idx = tid; idx < 9216; idx += 256) {
        int q = idx % 3;
        int p = (idx / 3) % 3;
        int i = (idx / 9) % 32;
        int o = idx / 288;
        float k = ks[idx];
        p1 += k * u1[i * 3 + q] * v1[o * 3 + p];
        p2 += k * u2[i * 3 + p] * v2[o * 3 + q];
        p3 += k * u3[i * 9 + p * 3 + q] * v3[o];
        p4 += k * u4[o * 9 + p * 3 + q] * v4[i];
    }
    float s1 = block_sum256(p1, red);
    float s2 = block_sum256(p2, red);
    float s3 = block_sum256(p3, red);
    float s4 = block_sum256(p4, red);
    float sigma = fminf(fminf(s1, s2), fminf(s3, s4));
    for (int idx = tid; idx < 9216; idx += 256)
        kf_out[idx] = ks[idx] / sigma;
}

// ---------------------------------------------------------------------------
// conv-exponential step, LDS-staged (this round):
// Per block (o,d): stage kf[o] (288 f) and ki[:,d] (32*S*S f, <=10.4 KB) into
// LDS once; the 121-px inner loop then runs entirely on LDS instead of 288
// scattered global loads per pixel (which was L2-latency-bound across 4
// sequential kernels). Loop order over (c,p,q) unchanged -> bit-identical.
// DOINIT fuses the old initacc_kernel into the first step: s accumulates into
// LDS sacc[121]; final write wacc = init(identity + centered kf) + sacc.
// ---------------------------------------------------------------------------
__global__ __launch_bounds__(128) void expstep_kernel(
    const float* __restrict__ kf, const float* __restrict__ ki,
    float* __restrict__ ko, float* __restrict__ wacc,
    int S, float scale, int doinit)
{
    __shared__ float kfs[288];
    __shared__ float kis[32 * 81];
    __shared__ float sacc[121];

    const int S2 = S + 2;
    const int SS = S * S;
    const int off = (11 - S2) >> 1;
    const int o = blockIdx.x >> 5;
    const int d = blockIdx.x & 31;
    const int tid = threadIdx.x;

    // stage kf[o] and ki[:,d]
    for (int i = tid; i < 288; i += 128) kfs[i] = kf[o * 288 + i];
    #pragma unroll 1
    for (int c = 0; c < 32; ++c)
        for (int i = tid; i < SS; i += 128)
            kis[c * SS + i] = ki[((c * 32 + d) * SS) + i];
    if (doinit)
        for (int j = tid; j < 121; j += 128) sacc[j] = 0.f;
    __syncthreads();

    for (int yx = tid; yx < S2 * S2; yx += 128) {
        int y = yx / S2, xx = yx - y * S2;
        float s = 0.f;
        for (int c = 0; c < 32; ++c) {
            const float* kfo = kfs + c * 9;
            const float* kic = kis + c * SS;
            #pragma unroll
            for (int p = 0; p < 3; ++p) {
                int yy = y - p;
                if (yy < 0 || yy >= S) continue;
                #pragma unroll
                for (int q = 0; q < 3; ++q) {
                    int xq = xx - q;
                    if (xq < 0 || xq >= S) continue;
                    s += kfo[p * 3 + q] * kic[yy * S + xq];
                }
            }
        }
        s *= scale;
        ko[(o * 32 + d) * S2 * S2 + yx] = s;
        if (doinit)
            sacc[(y + off) * 11 + (xx + off)] = s;
        else
            wacc[(o * 32 + d) * 121 + (y + off) * 11 + (xx + off)] += s;
    }

    if (doinit) {
        __syncthreads();
        for (int j = tid; j < 121; j += 128) {
            int y = j / 11, x = j - y * 11;
            float v = (o == d && y == 5 && x == 5) ? 1.0f : 0.0f;
            if (y >= 4 && y <= 6 && x >= 4 && x <= 6)
                v += kfs[d * 9 + (y - 4) * 3 + (x - 4)];
            wacc[(o * 32 + d) * 121 + j] = v + sacc[j];
        }
    }
}

// ---------------------------------------------------------------------------
// Weight prepack: wacc [o][c][11][11] fp32 -> wbuf bf16 A-fragments.
// Frag index = ((tap*2 + chalf)*2 + split)*64 + lane ; each entry = uint4
// (8 bf16): lane(m=lane&31, khalf=lane>>5), j -> c = chalf*16 + khalf*8 + j.
// split 0 = bf16 hi, split 1 = bf16 lo (residual).
// ---------------------------------------------------------------------------
__global__ void wprep_kernel(const float* __restrict__ wacc, uint4v* __restrict__ wbuf) {
    int idx = blockIdx.x * 256 + threadIdx.x;   // 121*2*2*64 = 30976
    if (idx >= 30976) return;
    int lane  = idx & 63;
    int split = (idx >> 6) & 1;
    int ch    = (idx >> 7) & 1;
    int tap   = idx >> 8;                       // p*11+q
    int o     = lane & 31;
    int cbase = ch * 16 + ((lane >> 5) << 3);
    unsigned short v[8];
    #pragma unroll
    for (int j = 0; j < 8; ++j) {
        float w = wacc[o * 3872 + (cbase + j) * 121 + tap];
        unsigned short h = bf16_rne(w);
        v[j] = split ? bf16_rne(w - bf16_to_f(h)) : h;
    }
    uint4v u;
    u.x = (unsigned)v[0] | ((unsigned)v[1] << 16);
    u.y = (unsigned)v[2] | ((unsigned)v[3] << 16);
    u.z = (unsigned)v[4] | ((unsigned)v[5] << 16);
    u.w = (unsigned)v[6] | ((unsigned)v[7] << 16);
    wbuf[idx] = u;
}

// ---------------------------------------------------------------------------
// Main conv via bf16-split MFMA (w=whi+wlo, x=xhi+xlo; 3 MFMAs per tap/c-half:
// Ahi*Bh + Alo*Bh + Ahi*Bl = w*x - wlo*xlo, rel err ~2^-16).
// EXACT round-2 version (best measured: 608 us conv). Row-reuse loop, split
// passes separated, B one row ahead, A-window 3 rows ahead, no setprio.
// Four controlled experiments (r1-r4: conflicts, ILP, stage overlap,
// occupancy) were all null/negative — this is the family optimum.
// LDS: plane-split pixel-major (SQ_LDS_BANK_CONFLICT = 0 verified).
// mfma_f32_32x32x16_bf16: A[m=lane&31][k=(lane>>5)*8+j], B[k][n=lane&31],
// D: col=lane&31, row=(r&3)+8*(r>>2)+4*(lane>>5)  [m74/m101 verified C/D].
// ---------------------------------------------------------------------------
__global__ __launch_bounds__(256, 2) void conv_mfma_kernel(
    const float* __restrict__ x, const uint4v* __restrict__ wbuf,
    const float* __restrict__ bias, float* __restrict__ out)
{
    __shared__ unsigned short shi[2 * 1092 * 8];   // [plane][px][8c] bf16 hi
    __shared__ unsigned short slo[2 * 1092 * 8];   // (lo)
    __shared__ float biasS[32];

    const int b    = blockIdx.z;
    const int Y0   = blockIdx.y << 4;
    const int X0   = blockIdx.x << 5;
    const int tid  = threadIdx.x;
    const int lane = tid & 63;
    const int ywave = (tid >> 6) << 2;                    // wave's first out row
    const int myoff = (lane & 31) + (lane >> 5) * 1092;   // 16B-unit offset

    if (tid < 32) biasS[tid] = bias[tid];

    f32x16 acc[4];
    #pragma unroll
    for (int s = 0; s < 4; ++s)
        #pragma unroll
        for (int r = 0; r < 16; ++r) acc[s][r] = 0.f;

    const uint4v* ph = (const uint4v*)shi;
    const uint4v* pl = (const uint4v*)slo;

    for (int chlf = 0; chlf < 2; ++chlf) {
        __syncthreads();   // previous readers done before restage
        // ---- stage patch (c-half), circular wrap, bf16 split ----
        const float* xb = x + (((size_t)(b * 32 + chlf * 16)) << 16);
        for (int pix = tid; pix < 1092; pix += 256) {
            int r = pix / 42, s = pix - r * 42;
            int gy = (Y0 + r - 5) & 255;
            int gx = (X0 + s - 5) & 255;
            const float* xp = xb + (gy << 8) + gx;
            unsigned short hv[16], lv[16];
            #pragma unroll
            for (int cc = 0; cc < 16; ++cc) {
                float v = xp[(size_t)cc << 16];
                unsigned short h = bf16_rne(v);
                hv[cc] = h;
                lv[cc] = bf16_rne(v - bf16_to_f(h));
            }
            uint4v u;
            u.x = (unsigned)hv[0] | ((unsigned)hv[1] << 16);
            u.y = (unsigned)hv[2] | ((unsigned)hv[3] << 16);
            u.z = (unsigned)hv[4] | ((unsigned)hv[5] << 16);
            u.w = (unsigned)hv[6] | ((unsigned)hv[7] << 16);
            *(uint4v*)&shi[pix * 8] = u;
            u.x = (unsigned)hv[8]  | ((unsigned)hv[9]  << 16);
            u.y = (unsigned)hv[10] | ((unsigned)hv[11] << 16);
            u.z = (unsigned)hv[12] | ((unsigned)hv[13] << 16);
            u.w = (unsigned)hv[14] | ((unsigned)hv[15] << 16);
            *(uint4v*)&shi[(1092 + pix) * 8] = u;
            u.x = (unsigned)lv[0] | ((unsigned)lv[1] << 16);
            u.y = (unsigned)lv[2] | ((unsigned)lv[3] << 16);
            u.z = (unsigned)lv[4] | ((unsigned)lv[5] << 16);
            u.w = (unsigned)lv[6] | ((unsigned)lv[7] << 16);
            *(uint4v*)&slo[pix * 8] = u;
            u.x = (unsigned)lv[8]  | ((unsigned)lv[9]  << 16);
            u.y = (unsigned)lv[10] | ((unsigned)lv[11] << 16);
            u.z = (unsigned)lv[12] | ((unsigned)lv[13] << 16);
            u.w = (unsigned)lv[14] | ((unsigned)lv[15] << 16);
            *(uint4v*)&slo[(1092 + pix) * 8] = u;
        }
        __syncthreads();

        // ---- row-reuse MFMA loop, A + B software-pipelined ----
        const int wb0 = chlf * 128 + lane;
        #pragma unroll 1
        for (int q = 0; q < 11; ++q) {
            uint4v ah[8], al[8];
            // prologue: taps p=0..2 for this q (window runs 3 rows ahead)
            ah[0] = wbuf[wb0 + q * 256];
            al[0] = wbuf[wb0 + q * 256 + 64];
            ah[1] = wbuf[wb0 + (11 + q) * 256];
            al[1] = wbuf[wb0 + (11 + q) * 256 + 64];
            ah[2] = wbuf[wb0 + (22 + q) * 256];
            al[2] = wbuf[wb0 + (22 + q) * 256 + 64];
            // B pipeline prologue: row 0
            bf16x8 Bh = __builtin_bit_cast(bf16x8, ph[ywave * 42 + q + myoff]);
            bf16x8 Bl = __builtin_bit_cast(bf16x8, pl[ywave * 42 + q + myoff]);
            #pragma unroll
            for (int r = 0; r < 14; ++r) {
                const bf16x8 cBh = Bh, cBl = Bl;
                if (r < 13) {   // issue next row's B reads before this row's MFMAs
                    const int basen = (ywave + r + 1) * 42 + q + myoff;
                    Bh = __builtin_bit_cast(bf16x8, ph[basen]);
                    Bl = __builtin_bit_cast(bf16x8, pl[basen]);
                }
                if (r + 3 <= 10) {   // A prefetch 3 rows ahead
                    ah[(r + 3) & 7] = wbuf[wb0 + ((r + 3) * 11 + q) * 256];
                    al[(r + 3) & 7] = wbuf[wb0 + ((r + 3) * 11 + q) * 256 + 64];
                }
                const int plo = (r - 3 > 0) ? r - 3 : 0;
                const int phi = (r < 10) ? r : 10;
                // pass 1: Ah*Bh  (independent accs between dependent pairs)
                #pragma unroll
                for (int p = plo; p <= phi; ++p)
                    acc[r - p] = __builtin_amdgcn_mfma_f32_32x32x16_bf16(
                        __builtin_bit_cast(bf16x8, ah[p & 7]), cBh, acc[r - p], 0, 0, 0);
                // pass 2: Al*Bh
                #pragma unroll
                for (int p = plo; p <= phi; ++p)
                    acc[r - p] = __builtin_amdgcn_mfma_f32_32x32x16_bf16(
                        __builtin_bit_cast(bf16x8, al[p & 7]), cBh, acc[r - p], 0, 0, 0);
                // pass 3: Ah*Bl
                #pragma unroll
                for (int p = plo; p <= phi; ++p)
                    acc[r - p] = __builtin_amdgcn_mfma_f32_32x32x16_bf16(
                        __builtin_bit_cast(bf16x8, ah[p & 7]), cBl, acc[r - p], 0, 0, 0);
            }
        }
    }

    // ---- epilogue: bias + store (lane = x col, reg -> o channel) ----
    const int colx = X0 + (lane & 31);
    const int half = lane >> 5;
    #pragma unroll
    for (int s = 0; s < 4; ++s) {
        int y = Y0 + ywave + s;
        #pragma unroll
        for (int r = 0; r < 16; ++r) {
            int o = (r & 3) + ((r >> 2) << 3) + (half << 2);
            out[(((size_t)(b * 32 + o)) << 16) + (y << 8) + colx] = acc[s][r] + biasS[o];
        }
    }
}

// ---------------------------------------------------------------------------
extern "C" void kernel_launch(void* const* d_in, const int* in_sizes, int n_in,
                              void* d_out, int out_size, void* d_ws, size_t ws_size,
                              hipStream_t stream) {
    const float* x    = (const float*)d_in[0];
    const float* wraw = (const float*)d_in[1];
    const float* bias = (const float*)d_in[2];
    const float* u1   = (const float*)d_in[3];
    const float* u2   = (const float*)d_in[4];
    const float* u3   = (const float*)d_in[5];
    const float* u4   = (const float*)d_in[6];
    float* out = (float*)d_out;

    float* ws   = (float*)d_ws;
    float* kf   = ws;               // 9216
    float* bufA = kf + 9216;        // 123904
    float* bufB = bufA + 123904;    // 123904
    float* wacc = bufB + 123904;    // 123904
    uint4v* wbuf = (uint4v*)(wacc + 123904);  // 30976 uint4 = 495616 B

    ff_kernel<<<1, 256, 0, stream>>>(wraw, u1, u2, u3, u4, kf);
    expstep_kernel<<<1024, 128, 0, stream>>>(kf, kf,   bufA, wacc, 3, 0.5f,      1);
    expstep_kernel<<<1024, 128, 0, stream>>>(kf, bufA, bufB, wacc, 5, 1.0f/3.0f, 0);
    expstep_kernel<<<1024, 128, 0, stream>>>(kf, bufB, bufA, wacc, 7, 0.25f,     0);
    expstep_kernel<<<1024, 128, 0, stream>>>(kf, bufA, bufB, wacc, 9, 0.2f,      0);
    wprep_kernel<<<121, 256, 0, stream>>>(wacc, wbuf);

    conv_mfma_kernel<<<dim3(8, 16, 16), 256, 0, stream>>>(x, wbuf, bias, out);
}

// Round 6
// 881.457 us; speedup vs baseline: 1.1070x; 1.0142x over previous
//
#include <hip/hip_runtime.h>
#include <math.h>

typedef __bf16 bf16x8 __attribute__((ext_vector_type(8)));
typedef float f32x16 __attribute__((ext_vector_type(16)));
typedef unsigned int uint4v __attribute__((ext_vector_type(4)));

__device__ __forceinline__ unsigned short bf16_rne(float f) {
    unsigned u = __float_as_uint(f);
    unsigned r = u + 0x7fffu + ((u >> 16) & 1u);
    return (unsigned short)(r >> 16);
}
__device__ __forceinline__ float bf16_to_f(unsigned short h) {
    return __uint_as_float(((unsigned)h) << 16);
}

// ---------------------------------------------------------------------------
__device__ __forceinline__ float block_sum256(float v, float* red) {
    #pragma unroll
    for (int off = 32; off > 0; off >>= 1)
        v += __shfl_down(v, off, 64);
    const int tid = threadIdx.x;
    if ((tid & 63) == 0) red[tid >> 6] = v;
    __syncthreads();
    float tot = red[0] + red[1] + red[2] + red[3];
    __syncthreads();
    return tot;
}

__device__ __forceinline__ void l2n_lds(float* a, int n, float* red) {
    float s = 0.f;
    for (int i = threadIdx.x; i < n; i += 256) s += a[i] * a[i];
    const float tot = block_sum256(s, red);
    const float sc = 1.0f / (sqrtf(tot) + 1e-12f);
    for (int i = threadIdx.x; i < n; i += 256) a[i] *= sc;
    __syncthreads();
}

// ---------------------------------------------------------------------------
// conv-exp step helper, fully in LDS. kin: zero-padded [c][13][14] (halo 2).
// kout (if !LAST): same layout, interior written at (+2,+2).
// Computes out[o,y,x] = scale * sum_c sum_pq kf[o,c,p,q]*kin[c,y-p,x-q]
// (padding zeros reproduce the original bounds checks exactly; c,p,q
// accumulation order preserved -> numerically identical).
// 4-px register tile per thread: 18 LDS reads + 9 kf reads per 36 FMA.
// ---------------------------------------------------------------------------
template<int SIN, bool LAST>
__device__ __forceinline__ void exp_step(
    const float* __restrict__ ks, const float* __restrict__ kin,
    float* __restrict__ kout, float* __restrict__ waccS,
    float scale, int tid)
{
    constexpr int S2  = SIN + 2;
    constexpr int OFF = (11 - S2) / 2;
    constexpr int NCH = (S2 + 3) / 4;
    constexpr int TOT = 32 * S2 * NCH;
    for (int ch = tid; ch < TOT; ch += 256) {
        int o   = ch / (S2 * NCH);
        int rem = ch - o * (S2 * NCH);
        int y   = rem / NCH;
        int x0  = (rem - y * NCH) * 4;
        float a0 = 0.f, a1 = 0.f, a2 = 0.f, a3 = 0.f;
        for (int c = 0; c < 32; ++c) {
            const float* kfo = ks + o * 288 + c * 9;
            #pragma unroll
            for (int p = 0; p < 3; ++p) {
                const float* row = kin + c * 182 + (y + 2 - p) * 14 + x0;
                float w0 = row[0], w1 = row[1], w2 = row[2];
                float w3 = row[3], w4 = row[4], w5 = row[5];
                float k0 = kfo[p * 3], k1 = kfo[p * 3 + 1], k2 = kfo[p * 3 + 2];
                a0 += k0 * w2; a0 += k1 * w1; a0 += k2 * w0;
                a1 += k0 * w3; a1 += k1 * w2; a1 += k2 * w1;
                a2 += k0 * w4; a2 += k1 * w3; a2 += k2 * w2;
                a3 += k0 * w5; a3 += k1 * w4; a3 += k2 * w3;
            }
        }
        a0 *= scale; a1 *= scale; a2 *= scale; a3 *= scale;
        float av[4] = {a0, a1, a2, a3};
        #pragma unroll
        for (int dx = 0; dx < 4; ++dx) {
            int xx = x0 + dx;
            if (xx < S2) {
                if (!LAST) kout[o * 182 + (y + 2) * 14 + (xx + 2)] = av[dx];
                waccS[o * 121 + (y + OFF) * 11 + (xx + OFF)] += av[dx];
            }
        }
    }
}

// ---------------------------------------------------------------------------
// FUSED weight pipeline: one kernel, 32 blocks (one per input channel d).
// Phase 1: ff (skew + fantastic_four) computed REDUNDANTLY per block —
//   identical inputs give bit-identical kf in each block's LDS; blocks run on
//   different CUs so replication costs no wall time. Kills the serial
//   1-block ff kernel launch + global kf round trip.
// Phase 2: conv-exp recurrence: the d-column is closed under
//   ki_next[o,d] = sum_c kf[o,c] (*) ki[c,d]  — block d keeps ki[:,d] in LDS
//   (zero-padded [c][13][14]) across all 4 steps, accumulating wacc[:,d] in
//   LDS too. Eliminates 4 expstep launches and all bufA/bufB HBM traffic.
// Numerics: identical operation order vs the previous 5-kernel pipeline.
// LDS: ks 36864 + 2*ki 46592 + wacc 15488 + ff vecs 4128 = ~103 KB (<160).
// ---------------------------------------------------------------------------
__global__ __launch_bounds__(256) void weight_kernel(
    const float* __restrict__ wr,
    const float* __restrict__ u1g, const float* __restrict__ u2g,
    const float* __restrict__ u3g, const float* __restrict__ u4g,
    float* __restrict__ wacc)
{
    __shared__ float ks[9216];
    __shared__ float kiA[32 * 182];
    __shared__ float kiB[32 * 182];
    __shared__ float waccS[32 * 121];
    __shared__ float u1[96], v1[96], u2[96], v2[96];
    __shared__ float u3[288], u4[288], v3[32], v4[32];
    __shared__ float red[8];
    const int tid = threadIdx.x;
    const int d   = blockIdx.x;

    // ===================== phase 1: ff =====================
    for (int i = tid; i < 9216; i += 256) {
        int q  = i % 3;
        int p  = (i / 3) % 3;
        int ic = (i / 9) % 32;
        int oc = i / 288;
        ks[i] = wr[i] - wr[ic * 288 + oc * 9 + (2 - p) * 3 + (2 - q)];
    }
    if (tid < 96) { u1[tid] = u1g[tid]; u2[tid] = u2g[tid]; }
    for (int i = tid; i < 288; i += 256) { u3[i] = u3g[i]; u4[i] = u4g[i]; }
    __syncthreads();
    l2n_lds(u1, 96, red);
    l2n_lds(u2, 96, red);
    l2n_lds(u3, 288, red);
    l2n_lds(u4, 288, red);

    for (int it = 0; it < 3; ++it) {
        if (tid < 96) {
            int o = tid / 3, p = tid % 3;
            float s = 0.f;
            for (int i = 0; i < 32; ++i)
                for (int q = 0; q < 3; ++q)
                    s += ks[o * 288 + i * 9 + p * 3 + q] * u1[i * 3 + q];
            v1[tid] = s;
        }
        __syncthreads();
        l2n_lds(v1, 96, red);
        if (tid < 96) {
            int i = tid / 3, q = tid % 3;
            float s = 0.f;
            for (int o = 0; o < 32; ++o)
                for (int p = 0; p < 3; ++p)
                    s += ks[o * 288 + i * 9 + p * 3 + q] * v1[o * 3 + p];
            u1[tid] = s;
        }
        __syncthreads();
        l2n_lds(u1, 96, red);
        if (tid < 96) {
            int o = tid / 3, q = tid % 3;
            float s = 0.f;
            for (int i = 0; i < 32; ++i)
                for (int p = 0; p < 3; ++p)
                    s += ks[o * 288 + i * 9 + p * 3 + q] * u2[i * 3 + p];
            v2[tid] = s;
        }
        __syncthreads();
        l2n_lds(v2, 96, red);
        if (tid < 96) {
            int i = tid / 3, p = tid % 3;
            float s = 0.f;
            for (int o = 0; o < 32; ++o)
                for (int q = 0; q < 3; ++q)
                    s += ks[o * 288 + i * 9 + p * 3 + q] * v2[o * 3 + q];
            u2[tid] = s;
        }
        __syncthreads();
        l2n_lds(u2, 96, red);
        if (tid < 32) {
            float s = 0.f;
            for (int i = 0; i < 32; ++i)
                for (int pq = 0; pq < 9; ++pq)
                    s += ks[tid * 288 + i * 9 + pq] * u3[i * 9 + pq];
            v3[tid] = s;
        }
        __syncthreads();
        l2n_lds(v3, 32, red);
        for (int j = tid; j < 288; j += 256) {
            float s = 0.f;
            for (int o = 0; o < 32; ++o)
                s += ks[o * 288 + j] * v3[o];
            u3[j] = s;
        }
        __syncthreads();
        l2n_lds(u3, 288, red);
        if (tid < 32) {
            float s = 0.f;
            for (int o = 0; o < 32; ++o)
                for (int pq = 0; pq < 9; ++pq)
                    s += ks[o * 288 + tid * 9 + pq] * u4[o * 9 + pq];
            v4[tid] = s;
        }
        __syncthreads();
        l2n_lds(v4, 32, red);
        for (int j = tid; j < 288; j += 256) {
            int o = j / 9, pq = j - o * 9;
            float s = 0.f;
            for (int i = 0; i < 32; ++i)
                s += ks[o * 288 + i * 9 + pq] * v4[i];
            u4[j] = s;
        }
        __syncthreads();
        l2n_lds(u4, 288, red);
    }

    float p1 = 0.f, p2 = 0.f, p3 = 0.f, p4 = 0.f;
    for (int idx = tid; idx < 9216; idx += 256) {
        int q = idx % 3;
        int p = (idx / 3) % 3;
        int i = (idx / 9) % 32;
        int o = idx / 288;
        float k = ks[idx];
        p1 += k * u1[i * 3 + q] * v1[o * 3 + p];
        p2 += k * u2[i * 3 + p] * v2[o * 3 + q];
        p3 += k * u3[i * 9 + p * 3 + q] * v3[o];
        p4 += k * u4[o * 9 + p * 3 + q] * v4[i];
    }
    float s1 = block_sum256(p1, red);
    float s2 = block_sum256(p2, red);
    float s3 = block_sum256(p3, red);
    float s4 = block_sum256(p4, red);
    float sigma = fminf(fminf(s1, s2), fminf(s3, s4));
    for (int idx = tid; idx < 9216; idx += 256)
        ks[idx] = ks[idx] / sigma;          // kf stays in LDS
    __syncthreads();

    // ===================== phase 2: conv-exp chain for column d ============
    // init: zero kiA; waccS = identity + centered kf (old initacc, c==d)
    for (int i = tid; i < 32 * 182; i += 256) kiA[i] = 0.f;
    for (int i = tid; i < 3872; i += 256) {
        int o = i / 121, j = i - o * 121;
        int y = j / 11, xx = j - y * 11;
        float v = (o == d && y == 5 && xx == 5) ? 1.0f : 0.0f;
        if (y >= 4 && y <= 6 && xx >= 4 && xx <= 6)
            v += ks[o * 288 + d * 9 + (y - 4) * 3 + (xx - 4)];
        waccS[i] = v;
    }
    __syncthreads();
    // fill ki_1 = kf[:,d] into kiA interior
    for (int i = tid; i < 288; i += 256) {
        int c = i / 9, t = i - c * 9;
        int yy = t / 3, xx = t - yy * 3;
        kiA[c * 182 + (yy + 2) * 14 + (xx + 2)] = ks[c * 288 + d * 9 + t];
    }
    __syncthreads();

    // step 2: S=3 -> 5 (kiA -> kiB)
    for (int i = tid; i < 32 * 182; i += 256) kiB[i] = 0.f;
    __syncthreads();
    exp_step<3, false>(ks, kiA, kiB, waccS, 0.5f, tid);
    __syncthreads();
    // step 3: S=5 -> 7 (kiB -> kiA)
    for (int i = tid; i < 32 * 182; i += 256) kiA[i] = 0.f;
    __syncthreads();
    exp_step<5, false>(ks, kiB, kiA, waccS, 1.0f / 3.0f, tid);
    __syncthreads();
    // step 4: S=7 -> 9 (kiA -> kiB)
    for (int i = tid; i < 32 * 182; i += 256) kiB[i] = 0.f;
    __syncthreads();
    exp_step<7, false>(ks, kiA, kiB, waccS, 0.25f, tid);
    __syncthreads();
    // step 5: S=9 -> 11 (kiB -> wacc only)
    exp_step<9, true>(ks, kiB, kiA, waccS, 0.2f, tid);
    __syncthreads();

    // write wacc[:, d] to global: layout [o][c=d][11][11]
    for (int i = tid; i < 3872; i += 256) {
        int o = i / 121, j = i - o * 121;
        wacc[(o * 32 + d) * 121 + j] = waccS[i];
    }
}

// ---------------------------------------------------------------------------
// Weight prepack: wacc [o][c][11][11] fp32 -> wbuf bf16 A-fragments.
// Frag index = ((tap*2 + chalf)*2 + split)*64 + lane ; each entry = uint4
// (8 bf16): lane(m=lane&31, khalf=lane>>5), j -> c = chalf*16 + khalf*8 + j.
// split 0 = bf16 hi, split 1 = bf16 lo (residual).
// ---------------------------------------------------------------------------
__global__ void wprep_kernel(const float* __restrict__ wacc, uint4v* __restrict__ wbuf) {
    int idx = blockIdx.x * 256 + threadIdx.x;   // 121*2*2*64 = 30976
    if (idx >= 30976) return;
    int lane  = idx & 63;
    int split = (idx >> 6) & 1;
    int ch    = (idx >> 7) & 1;
    int tap   = idx >> 8;                       // p*11+q
    int o     = lane & 31;
    int cbase = ch * 16 + ((lane >> 5) << 3);
    unsigned short v[8];
    #pragma unroll
    for (int j = 0; j < 8; ++j) {
        float w = wacc[o * 3872 + (cbase + j) * 121 + tap];
        unsigned short h = bf16_rne(w);
        v[j] = split ? bf16_rne(w - bf16_to_f(h)) : h;
    }
    uint4v u;
    u.x = (unsigned)v[0] | ((unsigned)v[1] << 16);
    u.y = (unsigned)v[2] | ((unsigned)v[3] << 16);
    u.z = (unsigned)v[4] | ((unsigned)v[5] << 16);
    u.w = (unsigned)v[6] | ((unsigned)v[7] << 16);
    wbuf[idx] = u;
}

// ---------------------------------------------------------------------------
// Main conv via bf16-split MFMA (w=whi+wlo, x=xhi+xlo; 3 MFMAs per tap/c-half:
// Ahi*Bh + Alo*Bh + Ahi*Bl = w*x - wlo*xlo, rel err ~2^-16).
// EXACT round-2 version (best measured: 608 us conv). Row-reuse loop, split
// passes separated, B one row ahead, A-window 3 rows ahead, no setprio.
// Four controlled experiments (r1-r4: conflicts, ILP, stage overlap,
// occupancy) were all null/negative — this is the family optimum.
// LDS: plane-split pixel-major (SQ_LDS_BANK_CONFLICT = 0 verified).
// mfma_f32_32x32x16_bf16: A[m=lane&31][k=(lane>>5)*8+j], B[k][n=lane&31],
// D: col=lane&31, row=(r&3)+8*(r>>2)+4*(lane>>5)  [m74/m101 verified C/D].
// ---------------------------------------------------------------------------
__global__ __launch_bounds__(256, 2) void conv_mfma_kernel(
    const float* __restrict__ x, const uint4v* __restrict__ wbuf,
    const float* __restrict__ bias, float* __restrict__ out)
{
    __shared__ unsigned short shi[2 * 1092 * 8];   // [plane][px][8c] bf16 hi
    __shared__ unsigned short slo[2 * 1092 * 8];   // (lo)
    __shared__ float biasS[32];

    const int b    = blockIdx.z;
    const int Y0   = blockIdx.y << 4;
    const int X0   = blockIdx.x << 5;
    const int tid  = threadIdx.x;
    const int lane = tid & 63;
    const int ywave = (tid >> 6) << 2;                    // wave's first out row
    const int myoff = (lane & 31) + (lane >> 5) * 1092;   // 16B-unit offset

    if (tid < 32) biasS[tid] = bias[tid];

    f32x16 acc[4];
    #pragma unroll
    for (int s = 0; s < 4; ++s)
        #pragma unroll
        for (int r = 0; r < 16; ++r) acc[s][r] = 0.f;

    const uint4v* ph = (const uint4v*)shi;
    const uint4v* pl = (const uint4v*)slo;

    for (int chlf = 0; chlf < 2; ++chlf) {
        __syncthreads();   // previous readers done before restage
        // ---- stage patch (c-half), circular wrap, bf16 split ----
        const float* xb = x + (((size_t)(b * 32 + chlf * 16)) << 16);
        for (int pix = tid; pix < 1092; pix += 256) {
            int r = pix / 42, s = pix - r * 42;
            int gy = (Y0 + r - 5) & 255;
            int gx = (X0 + s - 5) & 255;
            const float* xp = xb + (gy << 8) + gx;
            unsigned short hv[16], lv[16];
            #pragma unroll
            for (int cc = 0; cc < 16; ++cc) {
                float v = xp[(size_t)cc << 16];
                unsigned short h = bf16_rne(v);
                hv[cc] = h;
                lv[cc] = bf16_rne(v - bf16_to_f(h));
            }
            uint4v u;
            u.x = (unsigned)hv[0] | ((unsigned)hv[1] << 16);
            u.y = (unsigned)hv[2] | ((unsigned)hv[3] << 16);
            u.z = (unsigned)hv[4] | ((unsigned)hv[5] << 16);
            u.w = (unsigned)hv[6] | ((unsigned)hv[7] << 16);
            *(uint4v*)&shi[pix * 8] = u;
            u.x = (unsigned)hv[8]  | ((unsigned)hv[9]  << 16);
            u.y = (unsigned)hv[10] | ((unsigned)hv[11] << 16);
            u.z = (unsigned)hv[12] | ((unsigned)hv[13] << 16);
            u.w = (unsigned)hv[14] | ((unsigned)hv[15] << 16);
            *(uint4v*)&shi[(1092 + pix) * 8] = u;
            u.x = (unsigned)lv[0] | ((unsigned)lv[1] << 16);
            u.y = (unsigned)lv[2] | ((unsigned)lv[3] << 16);
            u.z = (unsigned)lv[4] | ((unsigned)lv[5] << 16);
            u.w = (unsigned)lv[6] | ((unsigned)lv[7] << 16);
            *(uint4v*)&slo[pix * 8] = u;
            u.x = (unsigned)lv[8]  | ((unsigned)lv[9]  << 16);
            u.y = (unsigned)lv[10] | ((unsigned)lv[11] << 16);
            u.z = (unsigned)lv[12] | ((unsigned)lv[13] << 16);
            u.w = (unsigned)lv[14] | ((unsigned)lv[15] << 16);
            *(uint4v*)&slo[(1092 + pix) * 8] = u;
        }
        __syncthreads();

        // ---- row-reuse MFMA loop, A + B software-pipelined ----
        const int wb0 = chlf * 128 + lane;
        #pragma unroll 1
        for (int q = 0; q < 11; ++q) {
            uint4v ah[8], al[8];
            // prologue: taps p=0..2 for this q (window runs 3 rows ahead)
            ah[0] = wbuf[wb0 + q * 256];
            al[0] = wbuf[wb0 + q * 256 + 64];
            ah[1] = wbuf[wb0 + (11 + q) * 256];
            al[1] = wbuf[wb0 + (11 + q) * 256 + 64];
            ah[2] = wbuf[wb0 + (22 + q) * 256];
            al[2] = wbuf[wb0 + (22 + q) * 256 + 64];
            // B pipeline prologue: row 0
            bf16x8 Bh = __builtin_bit_cast(bf16x8, ph[ywave * 42 + q + myoff]);
            bf16x8 Bl = __builtin_bit_cast(bf16x8, pl[ywave * 42 + q + myoff]);
            #pragma unroll
            for (int r = 0; r < 14; ++r) {
                const bf16x8 cBh = Bh, cBl = Bl;
                if (r < 13) {   // issue next row's B reads before this row's MFMAs
                    const int basen = (ywave + r + 1) * 42 + q + myoff;
                    Bh = __builtin_bit_cast(bf16x8, ph[basen]);
                    Bl = __builtin_bit_cast(bf16x8, pl[basen]);
                }
                if (r + 3 <= 10) {   // A prefetch 3 rows ahead
                    ah[(r + 3) & 7] = wbuf[wb0 + ((r + 3) * 11 + q) * 256];
                    al[(r + 3) & 7] = wbuf[wb0 + ((r + 3) * 11 + q) * 256 + 64];
                }
                const int plo = (r - 3 > 0) ? r - 3 : 0;
                const int phi = (r < 10) ? r : 10;
                // pass 1: Ah*Bh  (independent accs between dependent pairs)
                #pragma unroll
                for (int p = plo; p <= phi; ++p)
                    acc[r - p] = __builtin_amdgcn_mfma_f32_32x32x16_bf16(
                        __builtin_bit_cast(bf16x8, ah[p & 7]), cBh, acc[r - p], 0, 0, 0);
                // pass 2: Al*Bh
                #pragma unroll
                for (int p = plo; p <= phi; ++p)
                    acc[r - p] = __builtin_amdgcn_mfma_f32_32x32x16_bf16(
                        __builtin_bit_cast(bf16x8, al[p & 7]), cBh, acc[r - p], 0, 0, 0);
                // pass 3: Ah*Bl
                #pragma unroll
                for (int p = plo; p <= phi; ++p)
                    acc[r - p] = __builtin_amdgcn_mfma_f32_32x32x16_bf16(
                        __builtin_bit_cast(bf16x8, ah[p & 7]), cBl, acc[r - p], 0, 0, 0);
            }
        }
    }

    // ---- epilogue: bias + store (lane = x col, reg -> o channel) ----
    const int colx = X0 + (lane & 31);
    const int half = lane >> 5;
    #pragma unroll
    for (int s = 0; s < 4; ++s) {
        int y = Y0 + ywave + s;
        #pragma unroll
        for (int r = 0; r < 16; ++r) {
            int o = (r & 3) + ((r >> 2) << 3) + (half << 2);
            out[(((size_t)(b * 32 + o)) << 16) + (y << 8) + colx] = acc[s][r] + biasS[o];
        }
    }
}

// ---------------------------------------------------------------------------
extern "C" void kernel_launch(void* const* d_in, const int* in_sizes, int n_in,
                              void* d_out, int out_size, void* d_ws, size_t ws_size,
                              hipStream_t stream) {
    const float* x    = (const float*)d_in[0];
    const float* wraw = (const float*)d_in[1];
    const float* bias = (const float*)d_in[2];
    const float* u1   = (const float*)d_in[3];
    const float* u2   = (const float*)d_in[4];
    const float* u3   = (const float*)d_in[5];
    const float* u4   = (const float*)d_in[6];
    float* out = (float*)d_out;

    float* ws   = (float*)d_ws;
    float* wacc = ws;                         // 123904 floats
    uint4v* wbuf = (uint4v*)(wacc + 123904);  // 30976 uint4 = 495616 B

    weight_kernel<<<32, 256, 0, stream>>>(wraw, u1, u2, u3, u4, wacc);
    wprep_kernel<<<121, 256, 0, stream>>>(wacc, wbuf);
    conv_mfma_kernel<<<dim3(8, 16, 16), 256, 0, stream>>>(x, wbuf, bias, out);
}